// Round 4
// baseline (42.814 us; speedup 1.0000x reference)
//
#include <hip/hip_runtime.h>
#include <math.h>

#define NN 27
#define KD 28
#define HD 8192
#define HA_ 256
#define NO_ 5
#define NPAIR (KD*HD)      // 229376
#define HB 8               // h-columns per block
#define NBLK (HD/HB)       // 1024 blocks
#define SLOTS 64           // atomic accumulator copies (16 adds per address)

// ws layout: [0, SLOTS*KD) float accumulators; then one int counter.
// Zeroed per call by hipMemsetAsync (SLOTS*KD*4 + 4 bytes).

__global__ void __launch_bounds__(256, 4) kFused(const float* __restrict__ obs,
                                                 const int* __restrict__ adj,
                                                 const float* __restrict__ Wlin,
                                                 const float* __restrict__ Wattn,
                                                 const float* __restrict__ battn,
                                                 const float* __restrict__ W1,
                                                 const float* __restrict__ b1,
                                                 const float* __restrict__ W2,
                                                 const float* __restrict__ b2,
                                                 float* __restrict__ ws,
                                                 float* __restrict__ out) {
    __shared__ float P[HB][KD + 1];
    __shared__ float Q[HB][KD + 1];
    __shared__ float A[HB][KD];
    __shared__ unsigned adjm[NN];
    __shared__ float red[4][KD];
    __shared__ int isLast;

    const int t  = threadIdx.x;
    const int k  = t >> 3;            // 0..31 (k<28 active)
    const int hl = t & 7;
    const int h  = blockIdx.x * HB + hl;

    if (t < NN) {                     // pack adj column j into bits of adjm[j]
        unsigned m = 0;
        for (int i = 0; i < NN; ++i) m |= (adj[i * NN + t] != 0 ? 1u : 0u) << i;
        adjm[t] = m;
    }

    // ---- phase 1: this thread's 28 W values (the ONLY W_lin read); P/Q ----
    float4 wv[7];
    if (k < KD) {
        const float4* src = reinterpret_cast<const float4*>(
            Wlin + (size_t)k * NPAIR + (size_t)h * KD);
        const float4* wl4 = reinterpret_cast<const float4*>(Wattn);   // uniform
        const float4* wr4 = reinterpret_cast<const float4*>(Wattn + KD);
#pragma unroll
        for (int f4 = 0; f4 < 7; ++f4) wv[f4] = src[f4];
        float p = 0.f, q = 0.f;
#pragma unroll
        for (int f4 = 0; f4 < 7; ++f4) {
            float4 wl = wl4[f4], wr = wr4[f4], w = wv[f4];
            p += w.x * wl.x + w.y * wl.y + w.z * wl.z + w.w * wl.w;
            q += w.x * wr.x + w.y * wr.y + w.z * wr.z + w.w * wr.w;
        }
        P[hl][k] = p;
        Q[hl][k] = q;
    }
    __syncthreads();

    // ---- phase 2: softmax row idx -> A[hl][j]  (threads 0..215) ----
    if (t < HB * NN) {
        const int hl2 = t / NN, j = t - hl2 * NN;
        int idx = 0;
        for (int n = NN - 1; n >= 0; --n) if (obs[n] != 0.f) idx = n;
        const float bias = battn[0];
        const float p27 = P[hl2][27], q27 = Q[hl2][27];
        const float sj = Q[hl2][j] + (j == 1 ? q27 : 0.f) + bias;
        const unsigned msk = adjm[j];
        float mx = -3.0e38f;
#pragma unroll
        for (int i = 0; i < NN; ++i) {
            float e = P[hl2][i] + (i == 1 ? p27 : 0.f) + sj;
            e = e >= 0.f ? e : 0.2f * e;
            if (((msk >> i) & 1) && e > mx) mx = e;
        }
        float den = 0.f, num = 0.f;
#pragma unroll
        for (int i = 0; i < NN; ++i) {
            float e = P[hl2][i] + (i == 1 ? p27 : 0.f) + sj;
            e = e >= 0.f ? e : 0.2f * e;
            float x = ((msk >> i) & 1) ? __expf(e - mx) : 0.f;
            den += x;
            if (i == idx) num = x;    // i static, idx runtime
        }
        A[hl2][j] = num / den;
    }
    __syncthreads();

    // ---- phase 3: acc[f] = b[k,h]*w[f] from registers; reduce; atomicAdd ----
    float acc[KD];
    if (k < KD) {
        const float bk = A[hl][k < NN ? k : 1];   // node_emb = [I | (n==1)]
#pragma unroll
        for (int f4 = 0; f4 < 7; ++f4) {
            acc[4*f4+0] = bk * wv[f4].x;
            acc[4*f4+1] = bk * wv[f4].y;
            acc[4*f4+2] = bk * wv[f4].z;
            acc[4*f4+3] = bk * wv[f4].w;
        }
    } else {
#pragma unroll
        for (int f = 0; f < KD; ++f) acc[f] = 0.f;
    }
#pragma unroll
    for (int off = 32; off > 0; off >>= 1)
#pragma unroll
        for (int f = 0; f < KD; ++f) acc[f] += __shfl_xor(acc[f], off, 64);

    const int lane = t & 63, wv_id = t >> 6;
    if (lane == 0) {
#pragma unroll
        for (int f = 0; f < KD; ++f) red[wv_id][f] = acc[f];
    }
    __syncthreads();
    if (t < KD) {
        float partial = red[0][t] + red[1][t] + red[2][t] + red[3][t];
        atomicAdd(&ws[(blockIdx.x & (SLOTS - 1)) * KD + t], partial);
    }
    __syncthreads();                  // compiler drains vmcnt before s_barrier
    if (t == 0) {
        __threadfence();
        int* counter = (int*)(ws + SLOTS * KD);
        int old = atomicAdd(counter, 1);
        isLast = (old == NBLK - 1);
    }
    __syncthreads();

    // ---- last block: global reduce + MLP ----
    if (isLast) {
        __shared__ float x[KD];
        __shared__ float hh[HA_];
        if (t < KD) {
            float s = 0.f;
#pragma unroll 8
            for (int sl = 0; sl < SLOTS; ++sl)
                s += __hip_atomic_load(&ws[sl * KD + t], __ATOMIC_RELAXED,
                                       __HIP_MEMORY_SCOPE_AGENT);
            x[t] = s * (1.0f / HD);
        }
        __syncthreads();
        if (t < HA_) {
            float s = b1[t];
#pragma unroll
            for (int kk = 0; kk < KD; ++kk) s += x[kk] * W1[kk * HA_ + t];
            hh[t] = s >= 0.f ? s : 0.01f * s;
        }
        __syncthreads();
        if (t < NO_) {
            float s = b2[t];
            for (int u = 0; u < HA_; ++u) s += hh[u] * W2[u * NO_ + t];
            out[t] = s;
        }
    }
}

extern "C" void kernel_launch(void* const* d_in, const int* in_sizes, int n_in,
                              void* d_out, int out_size, void* d_ws, size_t ws_size,
                              hipStream_t stream) {
    const float* obs   = (const float*)d_in[0];
    const int*   adj   = (const int*)  d_in[2];
    const float* Wlin  = (const float*)d_in[3];
    const float* Wattn = (const float*)d_in[4];
    const float* battn = (const float*)d_in[5];
    const float* W1    = (const float*)d_in[6];
    const float* b1    = (const float*)d_in[7];
    const float* W2    = (const float*)d_in[8];
    const float* b2    = (const float*)d_in[9];
    float* ws  = (float*)d_ws;
    float* out = (float*)d_out;

    hipMemsetAsync(ws, 0, SLOTS * KD * sizeof(float) + sizeof(int), stream);
    kFused<<<NBLK, 256, 0, stream>>>(obs, adj, Wlin, Wattn, battn,
                                     W1, b1, W2, b2, ws, out);
}

// Round 5
// 40.366 us; speedup vs baseline: 1.0606x; 1.0606x over previous
//
#include <hip/hip_runtime.h>
#include <math.h>

#define NN 27
#define KD 28
#define HD 8192
#define HA_ 256
#define NO_ 5
#define NPAIR (KD*HD)      // 229376
#define HB 8               // h-columns per block
#define NBLK (HD/HB)       // 1024 blocks -> 4 blocks/CU, 16 waves/CU
#define SLOTS 64           // atomic accumulator copies (16 adds per address)

// ws layout: [0, SLOTS*KD) float accumulators; then one int counter.
// Zeroed per call by hipMemsetAsync (SLOTS*KD*4 + 4 bytes).

__global__ void __launch_bounds__(256, 4) kFused(const float* __restrict__ obs,
                                                 const int* __restrict__ adj,
                                                 const float* __restrict__ Wlin,
                                                 const float* __restrict__ Wattn,
                                                 const float* __restrict__ battn,
                                                 const float* __restrict__ W1,
                                                 const float* __restrict__ b1,
                                                 const float* __restrict__ W2,
                                                 const float* __restrict__ b2,
                                                 float* __restrict__ ws,
                                                 float* __restrict__ out) {
    __shared__ float P[HB][KD + 1];
    __shared__ float Q[HB][KD + 1];
    __shared__ float A[HB][KD];
    __shared__ unsigned adjm[NN];
    __shared__ float red[4][KD];
    __shared__ int isLast;

    const int t  = threadIdx.x;
    const int k  = t >> 3;            // 0..31 (k<28 active)
    const int hl = t & 7;
    const int h  = blockIdx.x * HB + hl;

    if (t < NN) {                     // pack adj column j into bits of adjm[j]
        unsigned m = 0;
        for (int i = 0; i < NN; ++i) m |= (adj[i * NN + t] != 0 ? 1u : 0u) << i;
        adjm[t] = m;
    }

    const float4* src = reinterpret_cast<const float4*>(
        Wlin + (size_t)(k < KD ? k : 0) * NPAIR + (size_t)h * KD);

    // ---- phase 1: read 28 W values, P/Q dots; values NOT retained ----
    if (k < KD) {
        const float4* wl4 = reinterpret_cast<const float4*>(Wattn);   // uniform
        const float4* wr4 = reinterpret_cast<const float4*>(Wattn + KD);
        float4 w[7];
#pragma unroll
        for (int f4 = 0; f4 < 7; ++f4) w[f4] = src[f4];
        float p = 0.f, q = 0.f;
#pragma unroll
        for (int f4 = 0; f4 < 7; ++f4) {
            float4 wl = wl4[f4], wr = wr4[f4];
            p += w[f4].x * wl.x + w[f4].y * wl.y + w[f4].z * wl.z + w[f4].w * wl.w;
            q += w[f4].x * wr.x + w[f4].y * wr.y + w[f4].z * wr.z + w[f4].w * wr.w;
        }
        P[hl][k] = p;
        Q[hl][k] = q;
    }
    __syncthreads();

    // ---- phase 2: softmax row idx -> A[hl][j]  (threads 0..215) ----
    if (t < HB * NN) {
        const int hl2 = t / NN, j = t - hl2 * NN;
        int idx = 0;
        for (int n = NN - 1; n >= 0; --n) if (obs[n] != 0.f) idx = n;
        const float bias = battn[0];
        const float p27 = P[hl2][27], q27 = Q[hl2][27];
        const float sj = Q[hl2][j] + (j == 1 ? q27 : 0.f) + bias;
        const unsigned msk = adjm[j];
        float mx = -3.0e38f;
#pragma unroll
        for (int i = 0; i < NN; ++i) {
            float e = P[hl2][i] + (i == 1 ? p27 : 0.f) + sj;
            e = e >= 0.f ? e : 0.2f * e;
            if (((msk >> i) & 1) && e > mx) mx = e;
        }
        float den = 0.f, num = 0.f;
#pragma unroll
        for (int i = 0; i < NN; ++i) {
            float e = P[hl2][i] + (i == 1 ? p27 : 0.f) + sj;
            e = e >= 0.f ? e : 0.2f * e;
            float x = ((msk >> i) & 1) ? __expf(e - mx) : 0.f;
            den += x;
            if (i == idx) num = x;    // i static, idx runtime
        }
        A[hl2][j] = num / den;
    }
    __syncthreads();

    // ---- phase 3: RE-read W (L2-resident slice), scale by b[k,h], reduce ----
    float acc[KD];
    if (k < KD) {
        const float bk = A[hl][k < NN ? k : 1];   // node_emb = [I | (n==1)]
#pragma unroll
        for (int f4 = 0; f4 < 7; ++f4) {
            float4 w = src[f4];
            acc[4*f4+0] = bk * w.x;
            acc[4*f4+1] = bk * w.y;
            acc[4*f4+2] = bk * w.z;
            acc[4*f4+3] = bk * w.w;
        }
    } else {
#pragma unroll
        for (int f = 0; f < KD; ++f) acc[f] = 0.f;
    }
#pragma unroll
    for (int off = 32; off > 0; off >>= 1)
#pragma unroll
        for (int f = 0; f < KD; ++f) acc[f] += __shfl_xor(acc[f], off, 64);

    const int lane = t & 63, wv_id = t >> 6;
    if (lane == 0) {
#pragma unroll
        for (int f = 0; f < KD; ++f) red[wv_id][f] = acc[f];
    }
    __syncthreads();
    if (t < KD) {
        float partial = red[0][t] + red[1][t] + red[2][t] + red[3][t];
        atomicAdd(&ws[(blockIdx.x & (SLOTS - 1)) * KD + t], partial);
    }
    __syncthreads();
    if (t == 0) {
        __threadfence();
        int* counter = (int*)(ws + SLOTS * KD);
        int old = atomicAdd(counter, 1);
        isLast = (old == NBLK - 1);
    }
    __syncthreads();

    // ---- last block: global reduce + MLP, parallelized tails ----
    if (isLast) {
        __shared__ float x[KD];
        __shared__ float hh[HA_];
        if (t < KD * 8) {                          // f = t>>3, slot-lane s = t&7
            const int f = t >> 3, s = t & 7;
            float v = 0.f;
#pragma unroll
            for (int b = 0; b < SLOTS / 8; ++b)
                v += __hip_atomic_load(&ws[(s + 8 * b) * KD + f],
                                       __ATOMIC_RELAXED, __HIP_MEMORY_SCOPE_AGENT);
            v += __shfl_xor(v, 1, 64);
            v += __shfl_xor(v, 2, 64);
            v += __shfl_xor(v, 4, 64);
            if (s == 0) x[f] = v * (1.0f / HD);
        }
        __syncthreads();
        {
            float s1 = b1[t];
#pragma unroll
            for (int kk = 0; kk < KD; ++kk) s1 += x[kk] * W1[kk * HA_ + t];
            hh[t] = s1 >= 0.f ? s1 : 0.01f * s1;
        }
        __syncthreads();
        if (t < 64) {
            float po[NO_];
#pragma unroll
            for (int o = 0; o < NO_; ++o) po[o] = 0.f;
#pragma unroll
            for (int u = 0; u < HA_ / 64; ++u) {
                const float hv = hh[t + 64 * u];
#pragma unroll
                for (int o = 0; o < NO_; ++o) po[o] += hv * W2[(t + 64 * u) * NO_ + o];
            }
#pragma unroll
            for (int off = 32; off > 0; off >>= 1)
#pragma unroll
                for (int o = 0; o < NO_; ++o) po[o] += __shfl_xor(po[o], off, 64);
            if (t == 0) {
#pragma unroll
                for (int o = 0; o < NO_; ++o) out[o] = po[o] + b2[o];
            }
        }
    }
}

extern "C" void kernel_launch(void* const* d_in, const int* in_sizes, int n_in,
                              void* d_out, int out_size, void* d_ws, size_t ws_size,
                              hipStream_t stream) {
    const float* obs   = (const float*)d_in[0];
    const int*   adj   = (const int*)  d_in[2];
    const float* Wlin  = (const float*)d_in[3];
    const float* Wattn = (const float*)d_in[4];
    const float* battn = (const float*)d_in[5];
    const float* W1    = (const float*)d_in[6];
    const float* b1    = (const float*)d_in[7];
    const float* W2    = (const float*)d_in[8];
    const float* b2    = (const float*)d_in[9];
    float* ws  = (float*)d_ws;
    float* out = (float*)d_out;

    hipMemsetAsync(ws, 0, SLOTS * KD * sizeof(float) + sizeof(int), stream);
    kFused<<<NBLK, 256, 0, stream>>>(obs, adj, Wlin, Wattn, battn,
                                     W1, b1, W2, b2, ws, out);
}

// Round 6
// 28.998 us; speedup vs baseline: 1.4764x; 1.3920x over previous
//
#include <hip/hip_runtime.h>
#include <math.h>

#define NN 27
#define KD 28
#define HD 8192
#define HA_ 256
#define NO_ 5
#define NPAIR (KD*HD)      // 229376
#define HB 32              // h-columns per block
#define NBLK (HD/HB)       // 256 blocks

// ws: NBLK*KD partial-x floats
__global__ void __launch_bounds__(256) kMain(const float* __restrict__ obs,
                                             const int* __restrict__ adj,
                                             const float* __restrict__ Wlin,
                                             const float* __restrict__ Wattn,
                                             const float* __restrict__ battn,
                                             float* __restrict__ ws) {
    __shared__ float P[HB][KD + 1];   // +1 pad: bank-conflict-free
    __shared__ float Q[HB][KD + 1];
    __shared__ float A[HB][KD];
    __shared__ unsigned adjm[NN];
    __shared__ float red[4][KD];

    const int t   = threadIdx.x;
    const int hl  = t >> 3;           // 0..31 local h
    const int sub = t & 7;            // 8 threads per h
    const int h   = blockIdx.x * HB + hl;

    // adjacency column masks (adj[i][j] for all i packed into bit i of adjm[j])
    if (t < NN) {
        unsigned m = 0;
        for (int i = 0; i < NN; ++i) m |= (adj[i * NN + t] != 0 ? 1u : 0u) << i;
        adjm[t] = m;
    }

    float wl[KD], wr[KD];             // uniform -> scalar regs
#pragma unroll
    for (int f = 0; f < KD; ++f) { wl[f] = Wattn[f]; wr[f] = Wattn[KD + f]; }

    // ---- phase 1: P[k,h], Q[k,h] from first read of W_lin ----
#pragma unroll
    for (int m = 0; m < 4; ++m) {
        int k = sub + 8 * m;
        if (k < KD) {
            const float4* w4 = reinterpret_cast<const float4*>(
                Wlin + (size_t)k * NPAIR + (size_t)h * KD);
            float p = 0.f, q = 0.f;
#pragma unroll
            for (int f4 = 0; f4 < 7; ++f4) {
                float4 w = w4[f4];
                p += w.x * wl[4*f4] + w.y * wl[4*f4+1] + w.z * wl[4*f4+2] + w.w * wl[4*f4+3];
                q += w.x * wr[4*f4] + w.y * wr[4*f4+1] + w.z * wr[4*f4+2] + w.w * wr[4*f4+3];
            }
            P[hl][k] = p;
            Q[hl][k] = q;
        }
    }
    __syncthreads();

    // idx = first nonzero of obs (uniform)
    int idx = 0;
    for (int n = NN - 1; n >= 0; --n) if (obs[n] != 0.f) idx = n;
    const float bias = battn[0];

    // ---- phase 2: softmax over i at row idx -> A[h][j] ----
    // node_emb = [I | (n==1)] by construction: s_i[n] = P[n] + (n==1)P[27]
    float si[NN];
#pragma unroll
    for (int i = 0; i < NN; ++i)
        si[i] = P[hl][i] + (i == 1 ? P[hl][27] : 0.f) + bias;

#pragma unroll
    for (int m = 0; m < 4; ++m) {
        int j = sub + 8 * m;
        if (j < NN) {
            float sj = Q[hl][j] + (j == 1 ? Q[hl][27] : 0.f);
            unsigned msk = adjm[j];
            float ev[NN];
            float mx = -3.0e38f;
#pragma unroll
            for (int i = 0; i < NN; ++i) {
                float e = si[i] + sj;
                e = e >= 0.f ? e : 0.2f * e;       // leaky 0.2
                ev[i] = e;
                if (((msk >> i) & 1) && e > mx) mx = e;
            }
            float den = 0.f, num = 0.f;
#pragma unroll
            for (int i = 0; i < NN; ++i) {
                float x = ((msk >> i) & 1) ? __expf(ev[i] - mx) : 0.f;
                den += x;
                if (i == idx) num = x;            // i static, idx runtime
            }
            A[hl][j] = num / den;
        }
    }
    __syncthreads();

    // ---- phase 3: x partials; b[k,h]=A[k] (k<27), A[1] (k==27); W re-read from L2 ----
    float acc[7][4];
#pragma unroll
    for (int f4 = 0; f4 < 7; ++f4)
#pragma unroll
        for (int c = 0; c < 4; ++c) acc[f4][c] = 0.f;

#pragma unroll
    for (int m = 0; m < 4; ++m) {
        int k = sub + 8 * m;
        if (k < KD) {
            float bk = (k < NN) ? A[hl][k] : A[hl][1];
            const float4* w4 = reinterpret_cast<const float4*>(
                Wlin + (size_t)k * NPAIR + (size_t)h * KD);
#pragma unroll
            for (int f4 = 0; f4 < 7; ++f4) {
                float4 w = w4[f4];
                acc[f4][0] += bk * w.x;
                acc[f4][1] += bk * w.y;
                acc[f4][2] += bk * w.z;
                acc[f4][3] += bk * w.w;
            }
        }
    }

    // reduce acc over the wave (butterfly), then across 4 waves via LDS
#pragma unroll
    for (int off = 32; off > 0; off >>= 1)
#pragma unroll
        for (int f4 = 0; f4 < 7; ++f4)
#pragma unroll
            for (int c = 0; c < 4; ++c)
                acc[f4][c] += __shfl_xor(acc[f4][c], off, 64);

    const int lane = t & 63, wv = t >> 6;
    if (lane == 0) {
#pragma unroll
        for (int f4 = 0; f4 < 7; ++f4)
#pragma unroll
            for (int c = 0; c < 4; ++c) red[wv][f4 * 4 + c] = acc[f4][c];
    }
    __syncthreads();
    if (t < KD)
        ws[blockIdx.x * KD + t] = red[0][t] + red[1][t] + red[2][t] + red[3][t];
}

// reduce 256 block-partials -> x, then MLP
__global__ void __launch_bounds__(512) kF(const float* __restrict__ W1,
                                          const float* __restrict__ b1,
                                          const float* __restrict__ W2,
                                          const float* __restrict__ b2,
                                          const float* __restrict__ ws,
                                          float* __restrict__ out) {
    __shared__ float xp[KD][16];
    __shared__ float x[KD];
    __shared__ float hh[HA_];
    int t = threadIdx.x;
    int f = t >> 4, seg = t & 15;
    if (f < KD) {
        float s = 0.f;
        for (int b = seg; b < NBLK; b += 16) s += ws[b * KD + f];
        xp[f][seg] = s;
    }
    __syncthreads();
    if (t < KD) {
        float s = 0.f;
#pragma unroll
        for (int g = 0; g < 16; ++g) s += xp[t][g];
        x[t] = s * (1.0f / HD);
    }
    __syncthreads();
    if (t < HA_) {
        float s = b1[t];
#pragma unroll
        for (int k = 0; k < KD; ++k) s += x[k] * W1[k * HA_ + t];
        hh[t] = s >= 0.f ? s : 0.01f * s;
    }
    __syncthreads();
    if (t < NO_) {
        float s = b2[t];
        for (int u = 0; u < HA_; ++u) s += hh[u] * W2[u * NO_ + t];
        out[t] = s;
    }
}

extern "C" void kernel_launch(void* const* d_in, const int* in_sizes, int n_in,
                              void* d_out, int out_size, void* d_ws, size_t ws_size,
                              hipStream_t stream) {
    const float* obs   = (const float*)d_in[0];
    const int*   adj   = (const int*)  d_in[2];
    const float* Wlin  = (const float*)d_in[3];
    const float* Wattn = (const float*)d_in[4];
    const float* battn = (const float*)d_in[5];
    const float* W1    = (const float*)d_in[6];
    const float* b1    = (const float*)d_in[7];
    const float* W2    = (const float*)d_in[8];
    const float* b2    = (const float*)d_in[9];
    float* ws  = (float*)d_ws;
    float* out = (float*)d_out;

    kMain<<<NBLK, 256, 0, stream>>>(obs, adj, Wlin, Wattn, battn, ws);
    kF<<<1, 512, 0, stream>>>(W1, b1, W2, b2, ws, out);
}